// Round 1
// baseline (379.819 us; speedup 1.0000x reference)
//
#include <hip/hip_runtime.h>
#include <hip/hip_bf16.h>

#define NB 128
#define NP 8732
#define NO 32
#define NC 21

// ---------------- workspace layout ----------------
// [0, 32768)            : unsigned long long packed[NB*NO]   (per-object argmax over priors)
// [32768, 33280)        : int npos[NB]
// [33280, 33792)        : double acc[3]  (0=pos_conf_sum, 1=loc_sum, 2=hard_neg_sum) + pad
// [33792, +NB*NP*4)     : int code[NB*NP]   (obj | forced/ovl>=0.5 flag<<8)
// [..., +NB*NP*4)       : float confneg[NB*NP]
// total ~ 9.0 MB

__global__ __launch_bounds__(256) void k_init(int* ws) {
    const int n = 33792 / 4;
    for (int i = threadIdx.x; i < n; i += 256) ws[i] = 0;
}

__global__ __launch_bounds__(256) void k_match(const float* __restrict__ boxes,
                                               const float* __restrict__ priors,
                                               int* __restrict__ code,
                                               unsigned long long* __restrict__ packed) {
    int b = blockIdx.y;
    int p = blockIdx.x * 256 + threadIdx.x;
    __shared__ float4 sbox[NO];
    if (threadIdx.x < NO)
        sbox[threadIdx.x] = ((const float4*)(boxes + (size_t)b * NO * 4))[threadIdx.x];
    __syncthreads();

    int pp = p < NP ? p : NP - 1;
    float4 pr = ((const float4*)priors)[pp];  // cxcy
    float px1 = pr.x - pr.z * 0.5f, py1 = pr.y - pr.w * 0.5f;
    float px2 = pr.x + pr.z * 0.5f, py2 = pr.y + pr.w * 0.5f;
    float pa = (px2 - px1) * (py2 - py1);

    float bestv = -1.0f;
    int besto = 0;
    int lane = threadIdx.x & 63;

    for (int o = 0; o < NO; ++o) {
        float4 bx = sbox[o];
        float lx = fmaxf(bx.x, px1), ly = fmaxf(bx.y, py1);
        float hx = fminf(bx.z, px2), hy = fminf(bx.w, py2);
        float iw = fmaxf(hx - lx, 0.0f), ih = fmaxf(hy - ly, 0.0f);
        float inter = iw * ih;
        float a1 = (bx.z - bx.x) * (bx.w - bx.y);
        float uni = a1 + pa - inter;
        float iou = inter / uni;
        if (iou > bestv) { bestv = iou; besto = o; }  // first max wins (strict >)

        // packed key: larger iou wins; tie -> smaller p wins (matches jnp.argmax)
        unsigned long long pk = 0ull;
        if (p < NP)
            pk = ((unsigned long long)__float_as_uint(iou) << 32) |
                 (unsigned long long)(0xFFFFFFFFu - (unsigned)p);
        for (int s = 32; s > 0; s >>= 1) {
            unsigned long long other = __shfl_xor(pk, s, 64);
            if (other > pk) pk = other;
        }
        if (lane == 0) atomicMax(&packed[b * NO + o], pk);
    }
    if (p < NP)
        code[(size_t)b * NP + p] = besto | (bestv >= 0.5f ? 256 : 0);
}

__global__ void k_force(int* __restrict__ code,
                        const unsigned long long* __restrict__ packed) {
    int b = threadIdx.x;
    if (b >= NB) return;
    for (int o = 0; o < NO; ++o) {  // sequential: last o wins (numpy scatter semantics)
        unsigned long long pk = packed[b * NO + o];
        unsigned p = 0xFFFFFFFFu - (unsigned)(pk & 0xFFFFFFFFull);
        if (p < NP) code[(size_t)b * NP + p] = o | 256;
    }
}

__global__ __launch_bounds__(256) void k_loss(const float* __restrict__ plocs,
                                              const float* __restrict__ scores,
                                              const float* __restrict__ boxes,
                                              const int* __restrict__ labels,
                                              const float* __restrict__ priors,
                                              const int* __restrict__ code,
                                              float* __restrict__ confneg,
                                              int* __restrict__ npos,
                                              double* __restrict__ acc) {
    int b = blockIdx.y;
    int p = blockIdx.x * 256 + threadIdx.x;
    float posconf = 0.0f, locpart = 0.0f;
    int isp = 0;

    if (p < NP) {
        int cd = code[(size_t)b * NP + p];
        int obj = cd & 255;
        int lbl = (cd & 256) ? labels[b * NO + obj] : 0;

        const float* s = scores + ((size_t)b * NP + p) * NC;
        float m = s[0];
#pragma unroll
        for (int c = 1; c < NC; ++c) m = fmaxf(m, s[c]);
        float sum = 0.0f;
#pragma unroll
        for (int c = 0; c < NC; ++c) sum += __expf(s[c] - m);
        float conf = m + __logf(sum) - s[lbl];

        if (lbl != 0) {
            isp = 1;
            posconf = conf;
            float4 bx = ((const float4*)boxes)[b * NO + obj];
            float4 pr = ((const float4*)priors)[p];
            float cx = (bx.x + bx.z) * 0.5f, cy = (bx.y + bx.w) * 0.5f;
            float w = bx.z - bx.x, h = bx.w - bx.y;
            float gx = (cx - pr.x) / (pr.z * 0.1f);
            float gy = (cy - pr.y) / (pr.w * 0.1f);
            float gw = __logf(w / pr.z) * 5.0f;
            float gh = __logf(h / pr.w) * 5.0f;
            float4 pl = ((const float4*)plocs)[(size_t)b * NP + p];
            locpart = fabsf(pl.x - gx) + fabsf(pl.y - gy) +
                      fabsf(pl.z - gw) + fabsf(pl.w - gh);
        }
        confneg[(size_t)b * NP + p] = isp ? 0.0f : conf;
    }

    __shared__ float r1[256], r2[256];
    __shared__ int rc[256];
    r1[threadIdx.x] = posconf;
    r2[threadIdx.x] = locpart;
    rc[threadIdx.x] = isp;
    __syncthreads();
    for (int st = 128; st > 0; st >>= 1) {
        if (threadIdx.x < st) {
            r1[threadIdx.x] += r1[threadIdx.x + st];
            r2[threadIdx.x] += r2[threadIdx.x + st];
            rc[threadIdx.x] += rc[threadIdx.x + st];
        }
        __syncthreads();
    }
    if (threadIdx.x == 0) {
        atomicAdd(&npos[b], rc[0]);
        atomicAdd(&acc[0], (double)r1[0]);
        atomicAdd(&acc[1], (double)r2[0]);
    }
}

__global__ __launch_bounds__(256) void k_topk(const float* __restrict__ confneg,
                                              const int* __restrict__ npos,
                                              double* __restrict__ acc) {
    __shared__ float row[NP];
    __shared__ int ci[4];
    __shared__ double cdbl[4];
    __shared__ int bcast;
    int tid = threadIdx.x, b = blockIdx.x;
    int lane = tid & 63, wid = tid >> 6;

    const float* src = confneg + (size_t)b * NP;
    for (int i = tid; i < NP; i += 256) row[i] = src[i];
    int k = npos[b] * 3;
    if (k > NP) k = NP;
    __syncthreads();
    if (k <= 0) return;  // block-uniform

    // bit-bisection for k-th largest value (all values >= 0 -> bits are ordered)
    unsigned T = 0;
    for (int bit = 30; bit >= 0; --bit) {
        unsigned cand = T | (1u << bit);
        int cnt = 0;
        for (int i = tid; i < NP; i += 256)
            cnt += (__float_as_uint(row[i]) >= cand) ? 1 : 0;
        for (int s = 32; s > 0; s >>= 1) cnt += __shfl_xor(cnt, s, 64);
        if (lane == 0) ci[wid] = cnt;
        __syncthreads();
        if (tid == 0) bcast = ci[0] + ci[1] + ci[2] + ci[3];
        __syncthreads();
        if (bcast >= k) T = cand;  // uniform decision
    }

    // sum of strictly-greater + fill with copies of the k-th value
    int cgt = 0;
    double sgt = 0.0;
    for (int i = tid; i < NP; i += 256) {
        unsigned u = __float_as_uint(row[i]);
        if (u > T) { cgt++; sgt += (double)row[i]; }
    }
    for (int s = 32; s > 0; s >>= 1) {
        cgt += __shfl_xor(cgt, s, 64);
        sgt += __shfl_xor(sgt, s, 64);
    }
    if (lane == 0) { ci[wid] = cgt; cdbl[wid] = sgt; }
    __syncthreads();
    if (tid == 0) {
        int cg = ci[0] + ci[1] + ci[2] + ci[3];
        double sg = cdbl[0] + cdbl[1] + cdbl[2] + cdbl[3];
        double total = sg + (double)(k - cg) * (double)__uint_as_float(T);
        atomicAdd(&acc[2], total);
    }
}

__global__ void k_final(const int* __restrict__ npos,
                        const double* __restrict__ acc,
                        float* __restrict__ out) {
    long nt = 0;
    for (int b = 0; b < NB; ++b) nt += npos[b];
    double conf = (acc[2] + acc[0]) / (double)nt;
    double loc = acc[1] / ((double)nt * 4.0);
    out[0] = (float)(conf + loc);
}

extern "C" void kernel_launch(void* const* d_in, const int* in_sizes, int n_in,
                              void* d_out, int out_size, void* d_ws, size_t ws_size,
                              hipStream_t stream) {
    const float* plocs  = (const float*)d_in[0];
    const float* scores = (const float*)d_in[1];
    const float* boxes  = (const float*)d_in[2];
    const int*   labels = (const int*)d_in[3];
    const float* priors = (const float*)d_in[4];
    float* out = (float*)d_out;

    char* ws = (char*)d_ws;
    unsigned long long* packed = (unsigned long long*)ws;
    int*    npos    = (int*)(ws + 32768);
    double* acc     = (double*)(ws + 33280);
    int*    code    = (int*)(ws + 33792);
    float*  confneg = (float*)(ws + 33792 + (size_t)NB * NP * 4);

    dim3 gridBP((NP + 255) / 256, NB);

    hipLaunchKernelGGL(k_init, dim3(1), dim3(256), 0, stream, (int*)ws);
    hipLaunchKernelGGL(k_match, gridBP, dim3(256), 0, stream, boxes, priors, code, packed);
    hipLaunchKernelGGL(k_force, dim3(1), dim3(128), 0, stream, code, packed);
    hipLaunchKernelGGL(k_loss, gridBP, dim3(256), 0, stream,
                       plocs, scores, boxes, labels, priors, code, confneg, npos, acc);
    hipLaunchKernelGGL(k_topk, dim3(NB), dim3(256), 0, stream, confneg, npos, acc);
    hipLaunchKernelGGL(k_final, dim3(1), dim3(1), 0, stream, npos, acc, out);
}

// Round 2
// 325.691 us; speedup vs baseline: 1.1662x; 1.1662x over previous
//
#include <hip/hip_runtime.h>
#include <hip/hip_bf16.h>

#define NB 128
#define NP 8732
#define NO 32
#define NC 21

// ---------------- workspace layout ----------------
// [0, 32768)            : unsigned long long packed[NB*NO]   (per-object argmax over priors)
// [32768, 33280)        : int npos[NB]
// [33280, 33792)        : double acc[3]  (0=pos_conf_sum, 1=loc_sum, 2=hard_neg_sum) + pad
// [33792, +NB*NP*4)     : int code[NB*NP]   (obj | matched-flag<<8)
// [..., +NB*NP*4)       : float confneg[NB*NP]

__global__ __launch_bounds__(256) void k_init(int* ws) {
    int i = blockIdx.x * 256 + threadIdx.x;
    const int n = 33792 / 4;
    if (i < n) ws[i] = 0;
}

// 4 priors per thread, strided by 256 within the block (coalesced).
__global__ __launch_bounds__(256) void k_match(const float* __restrict__ boxes,
                                               const float* __restrict__ priors,
                                               int* __restrict__ code,
                                               unsigned long long* __restrict__ packed) {
    int b = blockIdx.y;
    int base = blockIdx.x * 1024 + threadIdx.x;
    int lane = threadIdx.x & 63;

    __shared__ float4 sbox[NO];
    if (threadIdx.x < NO)
        sbox[threadIdx.x] = ((const float4*)(boxes + (size_t)b * NO * 4))[threadIdx.x];
    __syncthreads();

    int   pidx[4];
    float px1[4], py1[4], px2[4], py2[4], pa[4];
    float bestv[4];
    int   besto[4];
#pragma unroll
    for (int j = 0; j < 4; ++j) {
        int p = base + 256 * j;
        pidx[j] = p;
        int pp = p < NP ? p : NP - 1;
        float4 pr = ((const float4*)priors)[pp];
        px1[j] = pr.x - pr.z * 0.5f; py1[j] = pr.y - pr.w * 0.5f;
        px2[j] = pr.x + pr.z * 0.5f; py2[j] = pr.y + pr.w * 0.5f;
        pa[j]  = (px2[j] - px1[j]) * (py2[j] - py1[j]);
        bestv[j] = -1.0f; besto[j] = 0;
    }

    for (int o = 0; o < NO; ++o) {
        float4 bx = sbox[o];
        float a1 = (bx.z - bx.x) * (bx.w - bx.y);
        unsigned long long pk = 0ull;
#pragma unroll
        for (int j = 0; j < 4; ++j) {
            float lx = fmaxf(bx.x, px1[j]), ly = fmaxf(bx.y, py1[j]);
            float hx = fminf(bx.z, px2[j]), hy = fminf(bx.w, py2[j]);
            float iw = fmaxf(hx - lx, 0.0f), ih = fmaxf(hy - ly, 0.0f);
            float inter = iw * ih;
            float iou = inter / (a1 + pa[j] - inter);
            if (iou > bestv[j]) { bestv[j] = iou; besto[j] = o; }  // first max wins
            if (pidx[j] < NP) {
                // larger iou wins; tie -> smaller p (matches jnp.argmax)
                unsigned long long key =
                    ((unsigned long long)__float_as_uint(iou) << 32) |
                    (unsigned long long)(0xFFFFFFFFu - (unsigned)pidx[j]);
                if (key > pk) pk = key;
            }
        }
        for (int s = 32; s > 0; s >>= 1) {
            unsigned long long other = __shfl_xor(pk, s, 64);
            if (other > pk) pk = other;
        }
        if (lane == 0) atomicMax(&packed[b * NO + o], pk);
    }
#pragma unroll
    for (int j = 0; j < 4; ++j)
        if (pidx[j] < NP)
            code[(size_t)b * NP + pidx[j]] = besto[j] | (bestv[j] >= 0.5f ? 256 : 0);
}

__global__ void k_force(int* __restrict__ code,
                        const unsigned long long* __restrict__ packed) {
    int b = threadIdx.x;
    if (b >= NB) return;
    for (int o = 0; o < NO; ++o) {  // sequential: last o wins (numpy scatter semantics)
        unsigned long long pk = packed[b * NO + o];
        unsigned p = 0xFFFFFFFFu - (unsigned)(pk & 0xFFFFFFFFull);
        if (p < NP) code[(size_t)b * NP + p] = o | 256;
    }
}

// Scores staged through LDS with coalesced float4 loads.
__global__ __launch_bounds__(256) void k_loss(const float* __restrict__ plocs,
                                              const float* __restrict__ scores,
                                              const float* __restrict__ boxes,
                                              const int* __restrict__ labels,
                                              const float* __restrict__ priors,
                                              const int* __restrict__ code,
                                              float* __restrict__ confneg,
                                              int* __restrict__ npos,
                                              double* __restrict__ acc) {
    __shared__ float srow[256 * NC];  // 21504 B
    int b = blockIdx.y;
    int p0 = blockIdx.x * 256;
    int cnt = NP - p0; if (cnt > 256) cnt = 256;
    int nf4 = cnt * NC / 4;  // exact: 4 | cnt*21 for cnt in {256, 28}
    const float4* src4 = (const float4*)(scores + ((size_t)b * NP + p0) * NC);
    for (int i = threadIdx.x; i < nf4; i += 256)
        ((float4*)srow)[i] = src4[i];
    __syncthreads();

    int p = p0 + threadIdx.x;
    float posconf = 0.0f, locpart = 0.0f;
    int isp = 0;

    if (p < NP) {
        int cd = code[(size_t)b * NP + p];
        int obj = cd & 255;
        int lbl = (cd & 256) ? labels[b * NO + obj] : 0;

        const float* s = srow + threadIdx.x * NC;  // stride 21: bank-conflict-free
        float m = s[0];
#pragma unroll
        for (int c = 1; c < NC; ++c) m = fmaxf(m, s[c]);
        float sum = 0.0f;
#pragma unroll
        for (int c = 0; c < NC; ++c) sum += __expf(s[c] - m);
        float conf = m + __logf(sum) - s[lbl];

        if (lbl != 0) {
            isp = 1;
            posconf = conf;
            float4 bx = ((const float4*)boxes)[b * NO + obj];
            float4 pr = ((const float4*)priors)[p];
            float cx = (bx.x + bx.z) * 0.5f, cy = (bx.y + bx.w) * 0.5f;
            float w = bx.z - bx.x, h = bx.w - bx.y;
            float gx = (cx - pr.x) / (pr.z * 0.1f);
            float gy = (cy - pr.y) / (pr.w * 0.1f);
            float gw = __logf(w / pr.z) * 5.0f;
            float gh = __logf(h / pr.w) * 5.0f;
            float4 pl = ((const float4*)plocs)[(size_t)b * NP + p];
            locpart = fabsf(pl.x - gx) + fabsf(pl.y - gy) +
                      fabsf(pl.z - gw) + fabsf(pl.w - gh);
        }
        confneg[(size_t)b * NP + p] = isp ? 0.0f : conf;
    }

    __shared__ float r1[256], r2[256];
    __shared__ int rc[256];
    r1[threadIdx.x] = posconf;
    r2[threadIdx.x] = locpart;
    rc[threadIdx.x] = isp;
    __syncthreads();
    for (int st = 128; st > 0; st >>= 1) {
        if (threadIdx.x < st) {
            r1[threadIdx.x] += r1[threadIdx.x + st];
            r2[threadIdx.x] += r2[threadIdx.x + st];
            rc[threadIdx.x] += rc[threadIdx.x + st];
        }
        __syncthreads();
    }
    if (threadIdx.x == 0) {
        atomicAdd(&npos[b], rc[0]);
        atomicAdd(&acc[0], (double)r1[0]);
        atomicAdd(&acc[1], (double)r2[0]);
    }
}

// Exact k-th-largest by bit bisection; row values cached in registers.
__global__ __launch_bounds__(1024) void k_topk(const float* __restrict__ confneg,
                                               const int* __restrict__ npos,
                                               double* __restrict__ acc) {
    __shared__ int   si[16];
    __shared__ double sd[16];
    __shared__ int   sbcast;
    int tid = threadIdx.x, b = blockIdx.x;
    int lane = tid & 63, wid = tid >> 6;

    const float* src = confneg + (size_t)b * NP;
    float val[9];
#pragma unroll
    for (int j = 0; j < 9; ++j) {
        int i = tid + j * 1024;
        val[j] = (i < NP) ? src[i] : 0.0f;  // 0 never counts (cand>0, T>=0)
    }
    int k = npos[b] * 3;
    if (k > NP) k = NP;
    if (k <= 0) return;  // block-uniform

    unsigned T = 0;
    for (int bit = 30; bit >= 0; --bit) {
        unsigned cand = T | (1u << bit);
        int cnt = 0;
#pragma unroll
        for (int j = 0; j < 9; ++j)
            cnt += (__float_as_uint(val[j]) >= cand) ? 1 : 0;
        for (int s = 32; s > 0; s >>= 1) cnt += __shfl_xor(cnt, s, 64);
        if (lane == 0) si[wid] = cnt;
        __syncthreads();
        if (tid == 0) {
            int t = 0;
            for (int w = 0; w < 16; ++w) t += si[w];
            sbcast = t;
        }
        __syncthreads();
        if (sbcast >= k) T = cand;  // uniform decision
    }

    int cgt = 0;
    double sgt = 0.0;
#pragma unroll
    for (int j = 0; j < 9; ++j) {
        unsigned u = __float_as_uint(val[j]);
        if (u > T) { cgt++; sgt += (double)val[j]; }
    }
    for (int s = 32; s > 0; s >>= 1) {
        cgt += __shfl_xor(cgt, s, 64);
        sgt += __shfl_xor(sgt, s, 64);
    }
    if (lane == 0) { si[wid] = cgt; sd[wid] = sgt; }
    __syncthreads();
    if (tid == 0) {
        int cg = 0; double sg = 0.0;
        for (int w = 0; w < 16; ++w) { cg += si[w]; sg += sd[w]; }
        double total = sg + (double)(k - cg) * (double)__uint_as_float(T);
        atomicAdd(&acc[2], total);
    }
}

__global__ void k_final(const int* __restrict__ npos,
                        const double* __restrict__ acc,
                        float* __restrict__ out) {
    long nt = 0;
    for (int b = 0; b < NB; ++b) nt += npos[b];
    double conf = (acc[2] + acc[0]) / (double)nt;
    double loc = acc[1] / ((double)nt * 4.0);
    out[0] = (float)(conf + loc);
}

extern "C" void kernel_launch(void* const* d_in, const int* in_sizes, int n_in,
                              void* d_out, int out_size, void* d_ws, size_t ws_size,
                              hipStream_t stream) {
    const float* plocs  = (const float*)d_in[0];
    const float* scores = (const float*)d_in[1];
    const float* boxes  = (const float*)d_in[2];
    const int*   labels = (const int*)d_in[3];
    const float* priors = (const float*)d_in[4];
    float* out = (float*)d_out;

    char* ws = (char*)d_ws;
    unsigned long long* packed = (unsigned long long*)ws;
    int*    npos    = (int*)(ws + 32768);
    double* acc     = (double*)(ws + 33280);
    int*    code    = (int*)(ws + 33792);
    float*  confneg = (float*)(ws + 33792 + (size_t)NB * NP * 4);

    hipLaunchKernelGGL(k_init, dim3((33792 / 4 + 255) / 256), dim3(256), 0, stream, (int*)ws);
    hipLaunchKernelGGL(k_match, dim3((NP + 1023) / 1024, NB), dim3(256), 0, stream,
                       boxes, priors, code, packed);
    hipLaunchKernelGGL(k_force, dim3(1), dim3(128), 0, stream, code, packed);
    hipLaunchKernelGGL(k_loss, dim3((NP + 255) / 256, NB), dim3(256), 0, stream,
                       plocs, scores, boxes, labels, priors, code, confneg, npos, acc);
    hipLaunchKernelGGL(k_topk, dim3(NB), dim3(1024), 0, stream, confneg, npos, acc);
    hipLaunchKernelGGL(k_final, dim3(1), dim3(1), 0, stream, npos, acc, out);
}

// Round 3
// 248.678 us; speedup vs baseline: 1.5274x; 1.3097x over previous
//
#include <hip/hip_runtime.h>
#include <hip/hip_bf16.h>

#define NB 128
#define NP 8732
#define NO 32
#define NC 21

// ---------------- workspace layout ----------------
// [0, 32768)        : unsigned long long packed[NB*NO]  (per-object argmax over priors)
// [32768, 33280)    : int npos[NB]
// [33280, 36352)    : double accb[NB][3]  (0=pos_conf, 1=loc, 2=hard_neg)
// [36352, +NB*NP*4) : int code[NB*NP]     (obj | matched-flag<<8)
// [..., +NB*NP*4)   : float confneg[NB*NP]

__global__ __launch_bounds__(256) void k_init(int* ws) {
    int i = blockIdx.x * 256 + threadIdx.x;
    const int n = 36352 / 4;
    if (i < n) ws[i] = 0;
}

// 4 priors per thread, strided by 256 within the block (coalesced).
__global__ __launch_bounds__(256) void k_match(const float* __restrict__ boxes,
                                               const float* __restrict__ priors,
                                               int* __restrict__ code,
                                               unsigned long long* __restrict__ packed) {
    int b = blockIdx.y;
    int base = blockIdx.x * 1024 + threadIdx.x;
    int lane = threadIdx.x & 63;

    __shared__ float4 sbox[NO];
    if (threadIdx.x < NO)
        sbox[threadIdx.x] = ((const float4*)(boxes + (size_t)b * NO * 4))[threadIdx.x];
    __syncthreads();

    int   pidx[4];
    float px1[4], py1[4], px2[4], py2[4], pa[4];
    float bestv[4];
    int   besto[4];
#pragma unroll
    for (int j = 0; j < 4; ++j) {
        int p = base + 256 * j;
        pidx[j] = p;
        int pp = p < NP ? p : NP - 1;
        float4 pr = ((const float4*)priors)[pp];
        px1[j] = pr.x - pr.z * 0.5f; py1[j] = pr.y - pr.w * 0.5f;
        px2[j] = pr.x + pr.z * 0.5f; py2[j] = pr.y + pr.w * 0.5f;
        pa[j]  = (px2[j] - px1[j]) * (py2[j] - py1[j]);
        bestv[j] = -1.0f; besto[j] = 0;
    }

    for (int o = 0; o < NO; ++o) {
        float4 bx = sbox[o];
        float a1 = (bx.z - bx.x) * (bx.w - bx.y);
        unsigned long long pk = 0ull;
#pragma unroll
        for (int j = 0; j < 4; ++j) {
            float lx = fmaxf(bx.x, px1[j]), ly = fmaxf(bx.y, py1[j]);
            float hx = fminf(bx.z, px2[j]), hy = fminf(bx.w, py2[j]);
            float iw = fmaxf(hx - lx, 0.0f), ih = fmaxf(hy - ly, 0.0f);
            float inter = iw * ih;
            float iou = inter / (a1 + pa[j] - inter);
            if (iou > bestv[j]) { bestv[j] = iou; besto[j] = o; }  // first max wins
            if (pidx[j] < NP) {
                // larger iou wins; tie -> smaller p (matches jnp.argmax)
                unsigned long long key =
                    ((unsigned long long)__float_as_uint(iou) << 32) |
                    (unsigned long long)(0xFFFFFFFFu - (unsigned)pidx[j]);
                if (key > pk) pk = key;
            }
        }
        for (int s = 32; s > 0; s >>= 1) {
            unsigned long long other = __shfl_xor(pk, s, 64);
            if (other > pk) pk = other;
        }
        if (lane == 0) atomicMax(&packed[b * NO + o], pk);
    }
#pragma unroll
    for (int j = 0; j < 4; ++j)
        if (pidx[j] < NP)
            code[(size_t)b * NP + pidx[j]] = besto[j] | (bestv[j] >= 0.5f ? 256 : 0);
}

__global__ void k_force(int* __restrict__ code,
                        const unsigned long long* __restrict__ packed) {
    int b = threadIdx.x;
    if (b >= NB) return;
    for (int o = 0; o < NO; ++o) {  // sequential: last o wins (numpy scatter semantics)
        unsigned long long pk = packed[b * NO + o];
        unsigned p = 0xFFFFFFFFu - (unsigned)(pk & 0xFFFFFFFFull);
        if (p < NP) code[(size_t)b * NP + p] = o | 256;
    }
}

// Scores staged through LDS with coalesced float4 loads.
// Per-image accumulators (128-way spread) instead of same-address atomics.
__global__ __launch_bounds__(256) void k_loss(const float* __restrict__ plocs,
                                              const float* __restrict__ scores,
                                              const float* __restrict__ boxes,
                                              const int* __restrict__ labels,
                                              const float* __restrict__ priors,
                                              const int* __restrict__ code,
                                              float* __restrict__ confneg,
                                              int* __restrict__ npos,
                                              double* __restrict__ accb) {
    __shared__ float srow[256 * NC];  // 21504 B
    int b = blockIdx.y;
    int p0 = blockIdx.x * 256;
    int cnt = NP - p0; if (cnt > 256) cnt = 256;
    int nf4 = cnt * NC / 4;  // exact: 4 | cnt*21 for cnt in {256, 28}
    const float4* src4 = (const float4*)(scores + ((size_t)b * NP + p0) * NC);
    for (int i = threadIdx.x; i < nf4; i += 256)
        ((float4*)srow)[i] = src4[i];
    __syncthreads();

    int p = p0 + threadIdx.x;
    float posconf = 0.0f, locpart = 0.0f;
    int isp = 0;

    if (p < NP) {
        int cd = code[(size_t)b * NP + p];
        int obj = cd & 255;
        int lbl = (cd & 256) ? labels[b * NO + obj] : 0;

        const float* s = srow + threadIdx.x * NC;  // stride 21: bank-conflict-free
        float m = s[0];
#pragma unroll
        for (int c = 1; c < NC; ++c) m = fmaxf(m, s[c]);
        float sum = 0.0f;
#pragma unroll
        for (int c = 0; c < NC; ++c) sum += __expf(s[c] - m);
        float conf = m + __logf(sum) - s[lbl];

        if (lbl != 0) {
            isp = 1;
            posconf = conf;
            float4 bx = ((const float4*)boxes)[b * NO + obj];
            float4 pr = ((const float4*)priors)[p];
            float cx = (bx.x + bx.z) * 0.5f, cy = (bx.y + bx.w) * 0.5f;
            float w = bx.z - bx.x, h = bx.w - bx.y;
            float gx = (cx - pr.x) / (pr.z * 0.1f);
            float gy = (cy - pr.y) / (pr.w * 0.1f);
            float gw = __logf(w / pr.z) * 5.0f;
            float gh = __logf(h / pr.w) * 5.0f;
            float4 pl = ((const float4*)plocs)[(size_t)b * NP + p];
            locpart = fabsf(pl.x - gx) + fabsf(pl.y - gy) +
                      fabsf(pl.z - gw) + fabsf(pl.w - gh);
        }
        confneg[(size_t)b * NP + p] = isp ? 0.0f : conf;
    }

    // wave shuffle reduce, then 4-wave LDS combine, one barrier
    for (int s = 32; s > 0; s >>= 1) {
        posconf += __shfl_xor(posconf, s, 64);
        locpart += __shfl_xor(locpart, s, 64);
        isp     += __shfl_xor(isp, s, 64);
    }
    __shared__ float w0[4], w1[4];
    __shared__ int wc[4];
    int wid = threadIdx.x >> 6, lane = threadIdx.x & 63;
    if (lane == 0) { w0[wid] = posconf; w1[wid] = locpart; wc[wid] = isp; }
    __syncthreads();
    if (threadIdx.x == 0) {
        float t0 = w0[0] + w0[1] + w0[2] + w0[3];
        float t1 = w1[0] + w1[1] + w1[2] + w1[3];
        int   tc = wc[0] + wc[1] + wc[2] + wc[3];
        atomicAdd(&npos[b], tc);
        atomicAdd(&accb[b * 3 + 0], (double)t0);  // 34 blocks per address
        atomicAdd(&accb[b * 3 + 1], (double)t1);
    }
}

// Exact k-th-largest by bit bisection; one block per image; plain store (no atomic).
__global__ __launch_bounds__(1024) void k_topk(const float* __restrict__ confneg,
                                               const int* __restrict__ npos,
                                               double* __restrict__ accb) {
    __shared__ int   si[16];
    __shared__ double sd[16];
    __shared__ int   sbcast;
    int tid = threadIdx.x, b = blockIdx.x;
    int lane = tid & 63, wid = tid >> 6;

    const float* src = confneg + (size_t)b * NP;
    float val[9];
#pragma unroll
    for (int j = 0; j < 9; ++j) {
        int i = tid + j * 1024;
        val[j] = (i < NP) ? src[i] : 0.0f;  // 0 never counts (cand>0)
    }
    int k = npos[b] * 3;
    if (k > NP) k = NP;
    if (k <= 0) return;  // block-uniform; accb[b*3+2] stays 0 from k_init

    unsigned T = 0;
    for (int bit = 30; bit >= 0; --bit) {
        unsigned cand = T | (1u << bit);
        int cnt = 0;
#pragma unroll
        for (int j = 0; j < 9; ++j)
            cnt += (__float_as_uint(val[j]) >= cand) ? 1 : 0;
        for (int s = 32; s > 0; s >>= 1) cnt += __shfl_xor(cnt, s, 64);
        if (lane == 0) si[wid] = cnt;
        __syncthreads();
        if (tid == 0) {
            int t = 0;
            for (int w = 0; w < 16; ++w) t += si[w];
            sbcast = t;
        }
        __syncthreads();
        if (sbcast >= k) T = cand;  // uniform decision
    }

    int cgt = 0;
    double sgt = 0.0;
#pragma unroll
    for (int j = 0; j < 9; ++j) {
        unsigned u = __float_as_uint(val[j]);
        if (u > T) { cgt++; sgt += (double)val[j]; }
    }
    for (int s = 32; s > 0; s >>= 1) {
        cgt += __shfl_xor(cgt, s, 64);
        sgt += __shfl_xor(sgt, s, 64);
    }
    if (lane == 0) { si[wid] = cgt; sd[wid] = sgt; }
    __syncthreads();
    if (tid == 0) {
        int cg = 0; double sg = 0.0;
        for (int w = 0; w < 16; ++w) { cg += si[w]; sg += sd[w]; }
        accb[b * 3 + 2] = sg + (double)(k - cg) * (double)__uint_as_float(T);
    }
}

__global__ __launch_bounds__(128) void k_final(const int* __restrict__ npos,
                                               const double* __restrict__ accb,
                                               float* __restrict__ out) {
    int b = threadIdx.x;  // 0..127
    double pc = accb[b * 3 + 0];
    double lc = accb[b * 3 + 1];
    double hn = accb[b * 3 + 2];
    double np_ = (double)npos[b];
    for (int s = 32; s > 0; s >>= 1) {
        pc  += __shfl_xor(pc, s, 64);
        lc  += __shfl_xor(lc, s, 64);
        hn  += __shfl_xor(hn, s, 64);
        np_ += __shfl_xor(np_, s, 64);
    }
    __shared__ double sD[4][2];
    int wid = threadIdx.x >> 6, lane = threadIdx.x & 63;
    if (lane == 0) { sD[0][wid] = pc; sD[1][wid] = lc; sD[2][wid] = hn; sD[3][wid] = np_; }
    __syncthreads();
    if (threadIdx.x == 0) {
        double P = sD[0][0] + sD[0][1];
        double L = sD[1][0] + sD[1][1];
        double H = sD[2][0] + sD[2][1];
        double nt = sD[3][0] + sD[3][1];
        out[0] = (float)((H + P) / nt + L / (nt * 4.0));
    }
}

extern "C" void kernel_launch(void* const* d_in, const int* in_sizes, int n_in,
                              void* d_out, int out_size, void* d_ws, size_t ws_size,
                              hipStream_t stream) {
    const float* plocs  = (const float*)d_in[0];
    const float* scores = (const float*)d_in[1];
    const float* boxes  = (const float*)d_in[2];
    const int*   labels = (const int*)d_in[3];
    const float* priors = (const float*)d_in[4];
    float* out = (float*)d_out;

    char* ws = (char*)d_ws;
    unsigned long long* packed = (unsigned long long*)ws;
    int*    npos    = (int*)(ws + 32768);
    double* accb    = (double*)(ws + 33280);
    int*    code    = (int*)(ws + 36352);
    float*  confneg = (float*)(ws + 36352 + (size_t)NB * NP * 4);

    hipLaunchKernelGGL(k_init, dim3((36352 / 4 + 255) / 256), dim3(256), 0, stream, (int*)ws);
    hipLaunchKernelGGL(k_match, dim3((NP + 1023) / 1024, NB), dim3(256), 0, stream,
                       boxes, priors, code, packed);
    hipLaunchKernelGGL(k_force, dim3(1), dim3(128), 0, stream, code, packed);
    hipLaunchKernelGGL(k_loss, dim3((NP + 255) / 256, NB), dim3(256), 0, stream,
                       plocs, scores, boxes, labels, priors, code, confneg, npos, accb);
    hipLaunchKernelGGL(k_topk, dim3(NB), dim3(1024), 0, stream, confneg, npos, accb);
    hipLaunchKernelGGL(k_final, dim3(1), dim3(128), 0, stream, npos, accb, out);
}